// Round 3
// baseline (330.300 us; speedup 1.0000x reference)
//
#include <hip/hip_runtime.h>

// MultiplicativeAttention: B=8, QL=SL=2048, QD=SD=OD=512
//   qw = q@w; scores = qw@s^T (mask -> -1e10); attn_w = softmax(scores);
//   attn_out = (attn_w @ s) @ out_w^T + out_b
// Outputs (fp32, concat): attn_w [8*2048*2048], attn_out [8*2048*512]
//
// Round 3: fused scores+softmax+PV kernel (two-pass over raw scores with
// L3 read-back), swizzled bf16 operand layouts for conflict-free ds_read_b128.

#define NEG_INF -10000000000.0f
#define AS1 __attribute__((address_space(1)))
#define AS3 __attribute__((address_space(3)))

typedef __attribute__((ext_vector_type(8))) short short8;   // 8 bf16
typedef __attribute__((ext_vector_type(4))) float floatx4;  // MFMA acc / f32x4

__device__ __forceinline__ unsigned short f2u(float x) {
  unsigned int u = __float_as_uint(x);
  unsigned int r = (u + 0x7fffu + ((u >> 16) & 1u)) >> 16;
  return (unsigned short)r;
}

// ---------------------------------------------------------------------------
// cast fp32 [R][C] -> bf16 copy (dN) and/or transpose (dT), optionally with
// the k-XOR swizzle baked into the row layout: idx = row*len + (k ^ ((row&7)<<3))
template <int SWN, int SWT>
__global__ void cast_nt(const float* __restrict__ src,
                        unsigned short* __restrict__ dN,
                        unsigned short* __restrict__ dT, int R, int C) {
  __shared__ unsigned short t[32][33];
  const int b = blockIdx.z;
  const size_t boff = (size_t)b * R * C;
  const int r0 = blockIdx.y * 32, c0 = blockIdx.x * 32;
  const int tx = threadIdx.x;
  for (int i = threadIdx.y; i < 32; i += 8) {
    unsigned short u = f2u(src[boff + (size_t)(r0 + i) * C + c0 + tx]);
    t[i][tx] = u;
    if (dN) {
      int col = SWN ? ((c0 + tx) ^ (((r0 + i) & 7) << 3)) : (c0 + tx);
      dN[boff + (size_t)(r0 + i) * C + col] = u;
    }
  }
  __syncthreads();
  if (dT)
    for (int i = threadIdx.y; i < 32; i += 8) {
      int el = SWT ? ((r0 + tx) ^ (((c0 + i) & 7) << 3)) : (r0 + tx);
      dT[boff + (size_t)(c0 + i) * R + el] = t[tx][i];
    }
}

// ---------------------------------------------------------------------------
// Generic GEMM: C[m][n] = sum_k A[m][k]*Bt[n][k]. 128x128 tile, BK=32, 4 waves.
// AF32: A fp32 reg-staged; else bf16 via global_load_lds.
// OUT_MODE: 0 = bf16 out with XOR swizzle (feeds fused kernel); 2 = fp32+bias
template <int AF32, int OUT_MODE>
__global__ __launch_bounds__(256) void gemm_bt(
    const void* __restrict__ A_, const unsigned short* __restrict__ Bt_,
    void* __restrict__ C_, const float* __restrict__ bias, int N, int K) {
  __shared__ unsigned short As[128 * 32];
  __shared__ unsigned short Bs[128 * 32];

  const int tid = threadIdx.x;
  const int lane = tid & 63, wave = tid >> 6;
  const int wr = wave >> 1, wc = wave & 1;
  const int l16 = lane & 15, lh = lane >> 4;
  const int m0 = blockIdx.y * 128, n0 = blockIdx.x * 128;
  const unsigned short* Bt = Bt_;

  floatx4 acc[4][4] = {};

  for (int k0 = 0; k0 < K; k0 += 32) {
    float4 av[4];
    if constexpr (AF32) {
      const float* A = (const float*)A_;
#pragma unroll
      for (int i = 0; i < 4; ++i) {
        int e = (i * 256 + tid) * 4;
        int row = e >> 5, kk = e & 31;
        av[i] = *(const float4*)(A + (size_t)(m0 + row) * K + k0 + kk);
      }
    }
    __syncthreads();
    if constexpr (AF32) {
#pragma unroll
      for (int i = 0; i < 4; ++i) {
        int e = (i * 256 + tid) * 4;
        unsigned short b4[4] = {f2u(av[i].x), f2u(av[i].y), f2u(av[i].z), f2u(av[i].w)};
        *(uint2*)&As[e] = *(uint2*)b4;
      }
    } else {
      const unsigned short* A = (const unsigned short*)A_;
#pragma unroll
      for (int i = 0; i < 2; ++i) {
        int chunk = i * 4 + wave;
        int e = chunk * 512 + lane * 8;
        int row = e >> 5, kk = e & 31;
        __builtin_amdgcn_global_load_lds(
            (const AS1 void*)(A + (size_t)(m0 + row) * K + k0 + kk),
            (AS3 void*)(As + chunk * 512), 16, 0, 0);
      }
    }
#pragma unroll
    for (int i = 0; i < 2; ++i) {
      int chunk = i * 4 + wave;
      int e = chunk * 512 + lane * 8;
      int row = e >> 5, kk = e & 31;
      __builtin_amdgcn_global_load_lds(
          (const AS1 void*)(Bt + (size_t)(n0 + row) * K + k0 + kk),
          (AS3 void*)(Bs + chunk * 512), 16, 0, 0);
    }
    __syncthreads();

    short8 af[4], bfr[4];
#pragma unroll
    for (int m = 0; m < 4; ++m)
      af[m] = *(const short8*)&As[(wr * 64 + m * 16 + l16) * 32 + lh * 8];
#pragma unroll
    for (int n = 0; n < 4; ++n)
      bfr[n] = *(const short8*)&Bs[(wc * 64 + n * 16 + l16) * 32 + lh * 8];
#pragma unroll
    for (int m = 0; m < 4; ++m)
#pragma unroll
      for (int n = 0; n < 4; ++n)
        acc[m][n] = __builtin_amdgcn_mfma_f32_16x16x32_bf16(af[m], bfr[n], acc[m][n], 0, 0, 0);
  }

  const int rbase = m0 + wr * 64, cbase = n0 + wc * 64;
  if constexpr (OUT_MODE == 0) {
    unsigned short* C = (unsigned short*)C_;
#pragma unroll
    for (int m = 0; m < 4; ++m)
#pragma unroll
      for (int n = 0; n < 4; ++n) {
        int row = rbase + m * 16 + lh * 4;
        int col = cbase + n * 16 + l16;
#pragma unroll
        for (int j = 0; j < 4; ++j)
          C[(size_t)(row + j) * N + (col ^ (((row + j) & 7) << 3))] = f2u(acc[m][n][j]);
      }
  } else {
    float* C = (float*)C_;
#pragma unroll
    for (int n = 0; n < 4; ++n) {
      int col = cbase + n * 16 + l16;
      float bv = bias[col];
#pragma unroll
      for (int m = 0; m < 4; ++m) {
        int row = rbase + m * 16 + lh * 4;
#pragma unroll
        for (int j = 0; j < 4; ++j)
          C[(size_t)(row + j) * N + col] = acc[m][n][j] + bv;
      }
    }
  }
}

// ---------------------------------------------------------------------------
// Fused scores+mask+softmax+PV. One block per 64-row q-strip, 8 waves.
// Pass1: raw masked scores -> attn_w + online (max,sumexp). Pass2: read raw
// back (L3), normalize+write attn_w, PV-MFMA -> pre (bf16).
__global__ __launch_bounds__(512) void fused_attn(
    const unsigned short* __restrict__ qws,   // [16384][512] bf16 swizzled
    const unsigned short* __restrict__ sNs,   // [8][2048][512] bf16 swizzled
    const unsigned short* __restrict__ sTs,   // [8][512][2048] bf16 swizzled
    const int* __restrict__ maskg,            // [8][2048]
    float* __restrict__ attw,                 // [8][2048][2048]
    unsigned short* __restrict__ pre) {       // [16384][512] bf16 linear
  __shared__ __align__(16) char lds[141312];
  unsigned short* Astrip = (unsigned short*)lds;            // pass1: [64][512]
  unsigned short* B1 = (unsigned short*)(lds + 65536);      // pass1: 2x[256][64]
  unsigned short* B2 = (unsigned short*)lds;                // pass2: 2x[512][64]
  int* mlds = (int*)(lds + 131072);                         // [2048]
  float* stats = (float*)(lds + 131072 + 8192);             // [4][64][2]

  const int tid = threadIdx.x, lane = tid & 63, w = tid >> 6;
  const int l16 = lane & 15, lh = lane >> 4;
  const int z = blockIdx.x & 7, ms = blockIdx.x >> 3;
  const size_t qrow0 = (size_t)z * 2048 + ms * 64;

  const unsigned short* sNz = sNs + (size_t)z * 2048 * 512;
  const unsigned short* sTz = sTs + (size_t)z * 512 * 2048;
  float* attwB = attw + qrow0 * 2048;

  // ---- prologue: mask, qw strip (linear copy, swizzle baked), B1 chunk 0
#pragma unroll
  for (int i = 0; i < 4; ++i) mlds[i * 512 + tid] = maskg[z * 2048 + i * 512 + tid];
#pragma unroll
  for (int i = 0; i < 8; ++i)
    __builtin_amdgcn_global_load_lds(
        (const AS1 void*)(qws + qrow0 * 512 + i * 4096 + w * 512 + lane * 8),
        (AS3 void*)(Astrip + i * 4096 + w * 512), 16, 0, 0);
#pragma unroll
  for (int i = 0; i < 4; ++i) {
    int jl = (w * 4 + i) * 8 + (lane >> 3);
    __builtin_amdgcn_global_load_lds(
        (const AS1 void*)(sNz + (size_t)jl * 512 + (lane & 7) * 8),
        (AS3 void*)(B1 + (w * 4 + i) * 512), 16, 0, 0);
  }
  __syncthreads();

  const int wr = w >> 2, wc = w & 3;
  const int arow0 = wr * 32 + l16;
  const int asw = (arow0 & 7) << 3;        // row-XOR for A reads
  const int bsw = (l16 & 7) << 3;          // row-XOR for B reads (jl&7 == l16&7)
  const floatx4 fz = {};

  floatx4 acc1[2][4] = {};
  float mrun[2][4], srun[2][4];
#pragma unroll
  for (int m = 0; m < 2; ++m)
#pragma unroll
    for (int jj = 0; jj < 4; ++jj) { mrun[m][jj] = NEG_INF; srun[m][jj] = 0.f; }

  // ================= PASS 1: scores + raw write + online stats ==============
  for (int t = 0; t < 64; ++t) {
    const int cur = t & 1;
    if (t + 1 < 64) {
      const int j0n = ((t + 1) >> 3) * 256, kcn = ((t + 1) & 7) * 64;
#pragma unroll
      for (int i = 0; i < 4; ++i) {
        int jl = (w * 4 + i) * 8 + (lane >> 3);
        __builtin_amdgcn_global_load_lds(
            (const AS1 void*)(sNz + (size_t)(j0n + jl) * 512 + kcn + (lane & 7) * 8),
            (AS3 void*)(B1 + (cur ^ 1) * 16384 + (w * 4 + i) * 512), 16, 0, 0);
      }
    }
    const int kc = (t & 7) * 64;
#pragma unroll
    for (int ks = 0; ks < 2; ++ks) {
      const int kg = kc + ks * 32 + lh * 8;
      short8 a0 = *(const short8*)&Astrip[arow0 * 512 + (kg ^ asw)];
      short8 a1 = *(const short8*)&Astrip[(arow0 + 16) * 512 + (kg ^ asw)];
      const int kl = ks * 32 + lh * 8;
#pragma unroll
      for (int n = 0; n < 4; ++n) {
        int jl = wc * 64 + n * 16 + l16;
        short8 b = *(const short8*)&B1[cur * 16384 + jl * 64 + (kl ^ bsw)];
        acc1[0][n] = __builtin_amdgcn_mfma_f32_16x16x32_bf16(a0, b, acc1[0][n], 0, 0, 0);
        acc1[1][n] = __builtin_amdgcn_mfma_f32_16x16x32_bf16(a1, b, acc1[1][n], 0, 0, 0);
      }
    }
    if ((t & 7) == 7) {
      const int j0 = (t >> 3) * 256;
      bool keep[4];
#pragma unroll
      for (int n = 0; n < 4; ++n) keep[n] = mlds[j0 + wc * 64 + n * 16 + l16] != 0;
      float v[2][4][4];
#pragma unroll
      for (int m = 0; m < 2; ++m)
#pragma unroll
        for (int n = 0; n < 4; ++n)
#pragma unroll
          for (int jj = 0; jj < 4; ++jj)
            v[m][n][jj] = keep[n] ? acc1[m][n][jj] : NEG_INF;
#pragma unroll
      for (int m = 0; m < 2; ++m)
#pragma unroll
        for (int jj = 0; jj < 4; ++jj) {
          float tm = fmaxf(fmaxf(v[m][0][jj], v[m][1][jj]), fmaxf(v[m][2][jj], v[m][3][jj]));
#pragma unroll
          for (int o = 1; o < 16; o <<= 1) tm = fmaxf(tm, __shfl_xor(tm, o));
          float nm = fmaxf(mrun[m][jj], tm);
          float es = __expf(v[m][0][jj] - nm) + __expf(v[m][1][jj] - nm) +
                     __expf(v[m][2][jj] - nm) + __expf(v[m][3][jj] - nm);
#pragma unroll
          for (int o = 1; o < 16; o <<= 1) es += __shfl_xor(es, o);
          srun[m][jj] = srun[m][jj] * __expf(mrun[m][jj] - nm) + es;
          mrun[m][jj] = nm;
        }
#pragma unroll
      for (int m = 0; m < 2; ++m)
#pragma unroll
        for (int n = 0; n < 4; ++n) {
          int col = j0 + wc * 64 + n * 16 + l16;
#pragma unroll
          for (int jj = 0; jj < 4; ++jj) {
            int row = wr * 32 + m * 16 + lh * 4 + jj;
            attwB[(size_t)row * 2048 + col] = v[m][n][jj];
          }
        }
#pragma unroll
      for (int m = 0; m < 2; ++m)
#pragma unroll
        for (int n = 0; n < 4; ++n) acc1[m][n] = fz;
    }
    __syncthreads();
  }

  // ---- combine per-wave stats -> final (max, 1/sum) per row
  if (l16 == 0) {
#pragma unroll
    for (int m = 0; m < 2; ++m)
#pragma unroll
      for (int jj = 0; jj < 4; ++jj) {
        int row = wr * 32 + m * 16 + lh * 4 + jj;
        stats[(wc * 64 + row) * 2] = mrun[m][jj];
        stats[(wc * 64 + row) * 2 + 1] = srun[m][jj];
      }
  }
  __threadfence();
  __syncthreads();
  float fmr[2], fir[2];
#pragma unroll
  for (int m2 = 0; m2 < 2; ++m2) {
    int row = wr * 32 + m2 * 16 + l16;
    float ma = stats[(0 * 64 + row) * 2], mb = stats[(1 * 64 + row) * 2];
    float mc = stats[(2 * 64 + row) * 2], md = stats[(3 * 64 + row) * 2];
    float fm = fmaxf(fmaxf(ma, mb), fmaxf(mc, md));
    float fs = stats[(0 * 64 + row) * 2 + 1] * __expf(ma - fm) +
               stats[(1 * 64 + row) * 2 + 1] * __expf(mb - fm) +
               stats[(2 * 64 + row) * 2 + 1] * __expf(mc - fm) +
               stats[(3 * 64 + row) * 2 + 1] * __expf(md - fm);
    fmr[m2] = fm;
    fir[m2] = 1.0f / fs;
  }

  // ================= PASS 2: normalize + PV ==================================
#pragma unroll
  for (int i = 0; i < 8; ++i) {
    int dl = (w * 8 + i) * 8 + (lane >> 3);
    __builtin_amdgcn_global_load_lds(
        (const AS1 void*)(sTz + (size_t)dl * 2048 + (lane & 7) * 8),
        (AS3 void*)(B2 + (w * 8 + i) * 512), 16, 0, 0);
  }
  __syncthreads();

  floatx4 acc2[2][8] = {};
  const int r2a = wr * 32 + l16;
  for (int t = 0; t < 32; ++t) {
    const int cur = t & 1;
    // 1. raw reads (oldest in vm queue)
    floatx4 rv[2][2][2];
#pragma unroll
    for (int m2 = 0; m2 < 2; ++m2)
#pragma unroll
      for (int ks = 0; ks < 2; ++ks) {
        const float* pr = attwB + (size_t)(r2a + m2 * 16) * 2048 + t * 64 + ks * 32 + lh * 8;
        rv[m2][ks][0] = *(const floatx4*)pr;
        rv[m2][ks][1] = *(const floatx4*)(pr + 4);
      }
    // 2. issue next B2 chunk
    if (t + 1 < 32) {
      const int kb = (t + 1) * 64;
#pragma unroll
      for (int i = 0; i < 8; ++i) {
        int dl = (w * 8 + i) * 8 + (lane >> 3);
        __builtin_amdgcn_global_load_lds(
            (const AS1 void*)(sTz + (size_t)dl * 2048 + kb + (lane & 7) * 8),
            (AS3 void*)(B2 + (cur ^ 1) * 32768 + (w * 8 + i) * 512), 16, 0, 0);
      }
    }
    // 3. normalize
    float p[2][2][8];
#pragma unroll
    for (int m2 = 0; m2 < 2; ++m2)
#pragma unroll
      for (int ks = 0; ks < 2; ++ks)
#pragma unroll
        for (int e = 0; e < 4; ++e) {
          p[m2][ks][e] = __expf(rv[m2][ks][0][e] - fmr[m2]) * fir[m2];
          p[m2][ks][4 + e] = __expf(rv[m2][ks][1][e] - fmr[m2]) * fir[m2];
        }
    // 4. race guard: all raw reads of chunk t complete before writer stores
    if (t + 1 < 32)
      asm volatile("s_waitcnt vmcnt(8)\n\ts_barrier" ::: "memory");
    else
      asm volatile("s_waitcnt vmcnt(0)\n\ts_barrier" ::: "memory");
    // 5. designated wave writes normalized chunk
    if (wc == (t & 3)) {
#pragma unroll
      for (int m2 = 0; m2 < 2; ++m2)
#pragma unroll
        for (int ks = 0; ks < 2; ++ks) {
          float* pw = attwB + (size_t)(r2a + m2 * 16) * 2048 + t * 64 + ks * 32 + lh * 8;
          floatx4 lo = {p[m2][ks][0], p[m2][ks][1], p[m2][ks][2], p[m2][ks][3]};
          floatx4 hi = {p[m2][ks][4], p[m2][ks][5], p[m2][ks][6], p[m2][ks][7]};
          *(floatx4*)pw = lo;
          *(floatx4*)(pw + 4) = hi;
        }
    }
    // 6. cvt p -> bf16 A-frags
    short8 af[2][2];
#pragma unroll
    for (int m2 = 0; m2 < 2; ++m2)
#pragma unroll
      for (int ks = 0; ks < 2; ++ks) {
        short8 t8;
#pragma unroll
        for (int e = 0; e < 8; ++e) t8[e] = (short)f2u(p[m2][ks][e]);
        af[m2][ks] = t8;
      }
    // 7. PV MFMA
#pragma unroll
    for (int ks = 0; ks < 2; ++ks) {
      const int kl = ks * 32 + lh * 8;
#pragma unroll
      for (int n = 0; n < 8; ++n) {
        int d = wc * 128 + n * 16 + l16;
        short8 b = *(const short8*)&B2[cur * 32768 + d * 64 + (kl ^ bsw)];
        acc2[0][n] = __builtin_amdgcn_mfma_f32_16x16x32_bf16(af[0][ks], b, acc2[0][n], 0, 0, 0);
        acc2[1][n] = __builtin_amdgcn_mfma_f32_16x16x32_bf16(af[1][ks], b, acc2[1][n], 0, 0, 0);
      }
    }
    __syncthreads();
  }

  // epilogue: pre (bf16, linear)
  unsigned short* preB = pre + qrow0 * 512;
#pragma unroll
  for (int m2 = 0; m2 < 2; ++m2)
#pragma unroll
    for (int n = 0; n < 8; ++n) {
      int col = wc * 128 + n * 16 + l16;
#pragma unroll
      for (int jj = 0; jj < 4; ++jj) {
        int row = wr * 32 + m2 * 16 + lh * 4 + jj;
        preB[(size_t)row * 512 + col] = f2u(acc2[m2][n][jj]);
      }
    }
}

// ---------------------------------------------------------------------------
extern "C" void kernel_launch(void* const* d_in, const int* in_sizes, int n_in,
                              void* d_out, int out_size, void* d_ws, size_t ws_size,
                              hipStream_t stream) {
  const float* q = (const float*)d_in[0];      // [8,2048,512]
  const float* s = (const float*)d_in[1];      // [8,2048,512]
  const int* mask = (const int*)d_in[2];       // [8,1,2048]
  const float* w = (const float*)d_in[3];      // [512,512]
  const float* out_w = (const float*)d_in[4];  // [512,512]
  const float* out_b = (const float*)d_in[5];  // [512]

  float* attn_w = (float*)d_out;                              // [8,2048,2048]
  float* attn_out = (float*)d_out + (size_t)8 * 2048 * 2048;  // [8,2048,512]

  char* ws = (char*)d_ws;
  const size_t MB = 1024 * 1024;
  unsigned short* qws = (unsigned short*)(ws);            // [16384,512] swz
  unsigned short* sNs = (unsigned short*)(ws + 16 * MB);  // [8,2048,512] swz
  unsigned short* sTs = (unsigned short*)(ws + 32 * MB);  // [8,512,2048] swz
  unsigned short* pre = (unsigned short*)(ws + 48 * MB);  // [16384,512] linear
  unsigned short* wT  = (unsigned short*)(ws + 64 * MB);  // [512,512] linear
  unsigned short* owN = (unsigned short*)(ws + 65 * MB);  // [512,512] linear

  dim3 tb(32, 8);
  cast_nt<1, 1><<<dim3(16, 64, 8), tb, 0, stream>>>(s, sNs, sTs, 2048, 512);
  cast_nt<0, 0><<<dim3(16, 16, 1), tb, 0, stream>>>(w, nullptr, wT, 512, 512);
  cast_nt<0, 0><<<dim3(16, 16, 1), tb, 0, stream>>>(out_w, owN, nullptr, 512, 512);

  // GEMM1: qws = q @ w (bf16, swizzled rows)
  gemm_bt<1, 0><<<dim3(4, 128, 1), 256, 0, stream>>>(q, wT, qws, nullptr, 512, 512);

  // Fused: scores + mask + softmax -> attn_w; PV -> pre
  fused_attn<<<dim3(256), 512, 0, stream>>>(qws, sNs, sTs, mask, attn_w, pre);

  // GEMM4: attn_out = pre @ out_w^T + out_b (fp32 out)
  gemm_bt<0, 2><<<dim3(4, 128, 1), 256, 0, stream>>>(pre, owN, attn_out, out_b, 512, 512);

  (void)in_sizes; (void)n_in; (void)out_size; (void)ws_size;
}

// Round 4
// 212.773 us; speedup vs baseline: 1.5524x; 1.5524x over previous
//
#include <hip/hip_runtime.h>

// MultiplicativeAttention: B=8, QL=SL=2048, QD=SD=OD=512
//   qw = q@w; scores = qw@s^T (mask -> -1e10); attn_w = softmax(scores);
//   attn_out = (attn_w @ s) @ out_w^T + out_b
// Outputs (fp32, concat): attn_w [8*2048*2048], attn_out [8*2048*512]
//
// R4 pipeline:
//   cast s -> sN (bf16 linear) + sTs (bf16, row-swizzled); cast w, out_w
//   gemm1: qw = q @ w (bf16)
//   gemm_sc: masked scores -> fp16 raw packed in attn_w rows + partial stats
//   finalize_stats: partials -> per-row (max, 1/sum)
//   pv_norm: in-place normalize (raw fp16 -> p fp32 in attn_w) + PV MFMA -> pre
//   gemm4: attn_out = pre @ out_w^T + out_b

#define NEG_FILL -60000.0f  // fp16-exact mask fill; exp(NEG_FILL - m) == 0

#define AS1 __attribute__((address_space(1)))
#define AS3 __attribute__((address_space(3)))

typedef __attribute__((ext_vector_type(8))) short short8;   // 8 bf16/fp16
typedef __attribute__((ext_vector_type(4))) float floatx4;  // MFMA acc

__device__ __forceinline__ unsigned short f2u(float x) {  // f32 -> bf16 RNE
  unsigned int u = __float_as_uint(x);
  unsigned int r = (u + 0x7fffu + ((u >> 16) & 1u)) >> 16;
  return (unsigned short)r;
}
__device__ __forceinline__ unsigned short f2h(float x) {  // f32 -> fp16 bits
  _Float16 h = (_Float16)x;
  return __builtin_bit_cast(unsigned short, h);
}
__device__ __forceinline__ float h2f(unsigned short u) {  // fp16 bits -> f32
  _Float16 h = __builtin_bit_cast(_Float16, u);
  return (float)h;
}

// ---------------------------------------------------------------------------
// cast fp32 [R][C] -> bf16 copy (dN) and/or transpose (dT); SWT bakes the
// XOR-swizzle into dT's row layout: dT[d][k ^ ((d&7)<<3)] = src[k][d]
template <int SWT>
__global__ void cast_nt(const float* __restrict__ src,
                        unsigned short* __restrict__ dN,
                        unsigned short* __restrict__ dT, int R, int C) {
  __shared__ unsigned short t[32][33];
  const int b = blockIdx.z;
  const size_t boff = (size_t)b * R * C;
  const int r0 = blockIdx.y * 32, c0 = blockIdx.x * 32;
  const int tx = threadIdx.x;
  for (int i = threadIdx.y; i < 32; i += 8) {
    unsigned short u = f2u(src[boff + (size_t)(r0 + i) * C + c0 + tx]);
    t[i][tx] = u;
    if (dN) dN[boff + (size_t)(r0 + i) * C + c0 + tx] = u;
  }
  __syncthreads();
  if (dT)
    for (int i = threadIdx.y; i < 32; i += 8) {
      int d = c0 + i;  // dT row
      int k = r0 + tx; // dT col
      int el = SWT ? (k ^ ((d & 7) << 3)) : k;
      dT[boff + (size_t)d * R + el] = t[tx][i];
    }
}

// ---------------------------------------------------------------------------
// Generic GEMM: C[m][n] = sum_k A[m][k]*Bt[n][k]. 128x128 tile, BK=32, 4 waves.
// AF32: A fp32 reg-staged; else bf16 via global_load_lds.
// OUT_MODE: 0 = bf16 linear out; 2 = fp32 + bias
template <int AF32, int OUT_MODE>
__global__ __launch_bounds__(256) void gemm_bt(
    const void* __restrict__ A_, const unsigned short* __restrict__ Bt_,
    void* __restrict__ C_, const float* __restrict__ bias, int N, int K) {
  __shared__ unsigned short As[128 * 32];
  __shared__ unsigned short Bs[128 * 32];

  const int tid = threadIdx.x;
  const int lane = tid & 63, wave = tid >> 6;
  const int wr = wave >> 1, wc = wave & 1;
  const int l16 = lane & 15, lh = lane >> 4;
  const int m0 = blockIdx.y * 128, n0 = blockIdx.x * 128;
  const unsigned short* Bt = Bt_;

  floatx4 acc[4][4] = {};

  for (int k0 = 0; k0 < K; k0 += 32) {
    float4 av[4];
    if constexpr (AF32) {
      const float* A = (const float*)A_;
#pragma unroll
      for (int i = 0; i < 4; ++i) {
        int e = (i * 256 + tid) * 4;
        int row = e >> 5, kk = e & 31;
        av[i] = *(const float4*)(A + (size_t)(m0 + row) * K + k0 + kk);
      }
    }
    __syncthreads();
    if constexpr (AF32) {
#pragma unroll
      for (int i = 0; i < 4; ++i) {
        int e = (i * 256 + tid) * 4;
        unsigned short b4[4] = {f2u(av[i].x), f2u(av[i].y), f2u(av[i].z), f2u(av[i].w)};
        *(uint2*)&As[e] = *(uint2*)b4;
      }
    } else {
      const unsigned short* A = (const unsigned short*)A_;
#pragma unroll
      for (int i = 0; i < 2; ++i) {
        int chunk = i * 4 + wave;
        int e = chunk * 512 + lane * 8;
        int row = e >> 5, kk = e & 31;
        __builtin_amdgcn_global_load_lds(
            (const AS1 void*)(A + (size_t)(m0 + row) * K + k0 + kk),
            (AS3 void*)(As + chunk * 512), 16, 0, 0);
      }
    }
#pragma unroll
    for (int i = 0; i < 2; ++i) {
      int chunk = i * 4 + wave;
      int e = chunk * 512 + lane * 8;
      int row = e >> 5, kk = e & 31;
      __builtin_amdgcn_global_load_lds(
          (const AS1 void*)(Bt + (size_t)(n0 + row) * K + k0 + kk),
          (AS3 void*)(Bs + chunk * 512), 16, 0, 0);
    }
    __syncthreads();

    short8 af[4], bfr[4];
#pragma unroll
    for (int m = 0; m < 4; ++m)
      af[m] = *(const short8*)&As[(wr * 64 + m * 16 + l16) * 32 + lh * 8];
#pragma unroll
    for (int n = 0; n < 4; ++n)
      bfr[n] = *(const short8*)&Bs[(wc * 64 + n * 16 + l16) * 32 + lh * 8];
#pragma unroll
    for (int m = 0; m < 4; ++m)
#pragma unroll
      for (int n = 0; n < 4; ++n)
        acc[m][n] = __builtin_amdgcn_mfma_f32_16x16x32_bf16(af[m], bfr[n], acc[m][n], 0, 0, 0);
  }

  const int rbase = m0 + wr * 64, cbase = n0 + wc * 64;
  if constexpr (OUT_MODE == 0) {
    unsigned short* C = (unsigned short*)C_;
#pragma unroll
    for (int m = 0; m < 4; ++m)
#pragma unroll
      for (int n = 0; n < 4; ++n) {
        int row = rbase + m * 16 + lh * 4;
        int col = cbase + n * 16 + l16;
#pragma unroll
        for (int j = 0; j < 4; ++j)
          C[(size_t)(row + j) * N + col] = f2u(acc[m][n][j]);
      }
  } else {
    float* C = (float*)C_;
#pragma unroll
    for (int n = 0; n < 4; ++n) {
      int col = cbase + n * 16 + l16;
      float bv = bias[col];
#pragma unroll
      for (int m = 0; m < 4; ++m) {
        int row = rbase + m * 16 + lh * 4;
#pragma unroll
        for (int j = 0; j < 4; ++j)
          C[(size_t)(row + j) * N + col] = acc[m][n][j] + bv;
      }
    }
  }
}

// ---------------------------------------------------------------------------
// Scores + mask + partial softmax stats. Same tiling as gemm_bt<0,*>.
// Writes raw masked scores as fp16 PACKED into the attn_w fp32 row slots
// (first 4KB of each 8KB row), plus per-(block, wave-half) partial
// (max, sumexp) to statp[row][blockIdx.x*2 + wc].
__global__ __launch_bounds__(256) void gemm_sc(
    const unsigned short* __restrict__ qw,   // [16384][512] bf16
    const unsigned short* __restrict__ sN,   // [8][2048][512] bf16
    const int* __restrict__ maskg,           // [8][2048]
    float* __restrict__ attw,                // [16384][2048] fp32 slots
    float2* __restrict__ statp) {            // [16384][32]
  __shared__ unsigned short As[128 * 32];
  __shared__ unsigned short Bs[128 * 32];

  const int tid = threadIdx.x;
  const int lane = tid & 63, wave = tid >> 6;
  const int wr = wave >> 1, wc = wave & 1;
  const int l16 = lane & 15, lh = lane >> 4;
  const int z = blockIdx.z;
  const int m0 = blockIdx.y * 128, n0 = blockIdx.x * 128;
  const unsigned short* Ab = qw + ((size_t)z * 2048 + m0) * 512;
  const unsigned short* Bb = sN + ((size_t)z * 2048 + n0) * 512;

  floatx4 acc[4][4] = {};

  for (int k0 = 0; k0 < 512; k0 += 32) {
    __syncthreads();
#pragma unroll
    for (int i = 0; i < 2; ++i) {
      int chunk = i * 4 + wave;
      int e = chunk * 512 + lane * 8;
      int row = e >> 5, kk = e & 31;
      __builtin_amdgcn_global_load_lds(
          (const AS1 void*)(Ab + (size_t)row * 512 + k0 + kk),
          (AS3 void*)(As + chunk * 512), 16, 0, 0);
      __builtin_amdgcn_global_load_lds(
          (const AS1 void*)(Bb + (size_t)row * 512 + k0 + kk),
          (AS3 void*)(Bs + chunk * 512), 16, 0, 0);
    }
    __syncthreads();

    short8 af[4], bfr[4];
#pragma unroll
    for (int m = 0; m < 4; ++m)
      af[m] = *(const short8*)&As[(wr * 64 + m * 16 + l16) * 32 + lh * 8];
#pragma unroll
    for (int n = 0; n < 4; ++n)
      bfr[n] = *(const short8*)&Bs[(wc * 64 + n * 16 + l16) * 32 + lh * 8];
#pragma unroll
    for (int m = 0; m < 4; ++m)
#pragma unroll
      for (int n = 0; n < 4; ++n)
        acc[m][n] = __builtin_amdgcn_mfma_f32_16x16x32_bf16(af[m], bfr[n], acc[m][n], 0, 0, 0);
  }

  // epilogue: mask, raw fp16 write, partial stats
  bool keep[4];
#pragma unroll
  for (int n = 0; n < 4; ++n)
    keep[n] = maskg[z * 2048 + n0 + wc * 64 + n * 16 + l16] != 0;
#pragma unroll
  for (int m = 0; m < 4; ++m)
#pragma unroll
    for (int n = 0; n < 4; ++n)
      if (!keep[n]) {
        floatx4 f = {NEG_FILL, NEG_FILL, NEG_FILL, NEG_FILL};
        acc[m][n] = f;
      }

#pragma unroll
  for (int m = 0; m < 4; ++m)
#pragma unroll
    for (int j = 0; j < 4; ++j) {
      const int lrow = m0 + wr * 64 + m * 16 + lh * 4 + j;
      const size_t grow = (size_t)z * 2048 + lrow;
      unsigned short* rawrow = (unsigned short*)(attw + grow * 2048);
#pragma unroll
      for (int n = 0; n < 4; ++n)
        rawrow[n0 + wc * 64 + n * 16 + l16] = f2h(acc[m][n][j]);
      // stats over this wave-half's 64 cols
      float tm = fmaxf(fmaxf(acc[0 * 0 + m][0][j], acc[m][1][j]),
                       fmaxf(acc[m][2][j], acc[m][3][j]));
#pragma unroll
      for (int o = 1; o < 16; o <<= 1) tm = fmaxf(tm, __shfl_xor(tm, o));
      float es = __expf(acc[m][0][j] - tm) + __expf(acc[m][1][j] - tm) +
                 __expf(acc[m][2][j] - tm) + __expf(acc[m][3][j] - tm);
#pragma unroll
      for (int o = 1; o < 16; o <<= 1) es += __shfl_xor(es, o);
      if (l16 == 0) {
        float2 st = {tm, es};
        statp[grow * 32 + blockIdx.x * 2 + wc] = st;
      }
    }
}

// ---------------------------------------------------------------------------
// Combine 32 partials per row -> (max, 1/sum). 16384 rows.
__global__ __launch_bounds__(256) void finalize_stats(
    const float2* __restrict__ statp, float2* __restrict__ fstat) {
  const int r = blockIdx.x * 256 + threadIdx.x;
  const float2* p = statp + (size_t)r * 32;
  float fm = -3.4e38f;
#pragma unroll
  for (int i = 0; i < 32; ++i) fm = fmaxf(fm, p[i].x);
  float fs = 0.f;
#pragma unroll
  for (int i = 0; i < 32; ++i) fs += p[i].y * __expf(p[i].x - fm);
  float2 o = {fm, 1.0f / fs};
  fstat[r] = o;
}

// ---------------------------------------------------------------------------
// In-place normalize + PV. Block = 64 q-rows x N=512, 8 waves (wave w owns
// cols w*64..+64). Descending k-tiles so fp32 p-writes never clobber unread
// fp16 raw (write of tile u touches raw of tiles 2u,2u+1 > u).
// 2 raw barriers/tile, counted vmcnt(11) keeps next tile's B + raw in flight.
__global__ __launch_bounds__(512) void pv_norm(
    float* __restrict__ attw,                 // rows: fp16 raw -> fp32 p
    const unsigned short* __restrict__ sTs,   // [8][512][2048] swizzled
    const float2* __restrict__ fstat,         // [16384] (max, 1/sum)
    unsigned short* __restrict__ pre) {       // [16384][512] bf16
  __shared__ unsigned short Bsl[2][512 * 64];  // 128 KB
  __shared__ unsigned short Pl[64 * 64];       // 8 KB
  const int tid = threadIdx.x, lane = tid & 63, w = tid >> 6;
  const int l16 = lane & 15, lh = lane >> 4;
  const int z = blockIdx.x & 7, ms = blockIdx.x >> 3;  // batch -> XCD pinning
  const size_t qrow0 = (size_t)z * 2048 + ms * 64;
  const unsigned short* Bz = sTs + (size_t)z * 512 * 2048;
  float* attwB = attw + qrow0 * 2048;
  const int prow = tid >> 3, pkc = (tid & 7) * 8;
  const unsigned short* rawrow = (const unsigned short*)(attwB + (size_t)prow * 2048);
  float* prowp = attwB + (size_t)prow * 2048;
  float2 st = fstat[qrow0 + prow];
  const float fm = st.x, inv = st.y;
  const int bd = w * 8 + (lane >> 3);  // staging d-row (per thread) within chunk
  const int bkk = (lane & 7) * 8;
  const int psw = (prow & 7) << 3;
  const int fsw = (l16 & 7) << 3;

  floatx4 acc[4][4] = {};

  // prologue: raw(31) + B(31) in flight
  short8 rv = *(const short8*)(rawrow + 31 * 64 + pkc);
#pragma unroll
  for (int i = 0; i < 8; ++i) {
    int d = i * 64 + bd;
    __builtin_amdgcn_global_load_lds(
        (const AS1 void*)(Bz + (size_t)d * 2048 + 31 * 64 + bkk),
        (AS3 void*)(&Bsl[0][(size_t)d * 64 + bkk]), 16, 0, 0);
  }

  for (int t = 31; t >= 0; --t) {
    const int cur = (31 - t) & 1;
    // (a) normalize tile t (compiler waits rv's vmcnt)
    float p[8];
#pragma unroll
    for (int e = 0; e < 8; ++e)
      p[e] = __expf(h2f((unsigned short)rv[e]) - fm) * inv;
    // (b) fp32 p -> attn_w (2 dwordx4 stores)
    float4 lo = {p[0], p[1], p[2], p[3]};
    float4 hi = {p[4], p[5], p[6], p[7]};
    *(float4*)(prowp + t * 64 + pkc) = lo;
    *(float4*)(prowp + t * 64 + pkc + 4) = hi;
    // (c,d) prefetch tile t-1 (raw + B)
    short8 rvn = rv;
    if (t > 0) {
      rvn = *(const short8*)(rawrow + (t - 1) * 64 + pkc);
#pragma unroll
      for (int i = 0; i < 8; ++i) {
        int d = i * 64 + bd;
        __builtin_amdgcn_global_load_lds(
            (const AS1 void*)(Bz + (size_t)d * 2048 + (t - 1) * 64 + bkk),
            (AS3 void*)(&Bsl[cur ^ 1][(size_t)d * 64 + bkk]), 16, 0, 0);
      }
    }
    // (e) p -> bf16 -> Pl (swizzled)
    short8 pb;
#pragma unroll
    for (int e = 0; e < 8; ++e) pb[e] = (short)f2u(p[e]);
    *(short8*)&Pl[prow * 64 + (pkc ^ psw)] = pb;
    asm volatile("s_waitcnt lgkmcnt(0)" ::: "memory");
    if (t > 0)
      asm volatile("s_waitcnt vmcnt(11)" ::: "memory");  // B(t) done; B(t-1)+raw+stores in flight
    else
      asm volatile("s_waitcnt vmcnt(2)" ::: "memory");
    __builtin_amdgcn_sched_barrier(0);
    __builtin_amdgcn_s_barrier();
    __builtin_amdgcn_sched_barrier(0);
    // frag reads + 32 MFMA
    short8 af[4][2], bf2[4][2];
#pragma unroll
    for (int m = 0; m < 4; ++m)
#pragma unroll
      for (int ks = 0; ks < 2; ++ks)
        af[m][ks] = *(const short8*)&Pl[(m * 16 + l16) * 64 + ((ks * 32 + lh * 8) ^ fsw)];
#pragma unroll
    for (int n = 0; n < 4; ++n)
#pragma unroll
      for (int ks = 0; ks < 2; ++ks)
        bf2[n][ks] = *(const short8*)&Bsl[cur][(w * 64 + n * 16 + l16) * 64 +
                                              ((ks * 32 + lh * 8) ^ fsw)];
#pragma unroll
    for (int ks = 0; ks < 2; ++ks)
#pragma unroll
      for (int m = 0; m < 4; ++m)
#pragma unroll
        for (int n = 0; n < 4; ++n)
          acc[m][n] = __builtin_amdgcn_mfma_f32_16x16x32_bf16(af[m][ks], bf2[n][ks],
                                                              acc[m][n], 0, 0, 0);
    asm volatile("s_waitcnt lgkmcnt(0)" ::: "memory");
    __builtin_amdgcn_sched_barrier(0);
    __builtin_amdgcn_s_barrier();
    rv = rvn;
  }

  // epilogue: pre (bf16, linear)
  unsigned short* preB = pre + qrow0 * 512;
#pragma unroll
  for (int m = 0; m < 4; ++m)
#pragma unroll
    for (int n = 0; n < 4; ++n) {
      int row = m * 16 + lh * 4;
      int col = w * 64 + n * 16 + l16;
#pragma unroll
      for (int j = 0; j < 4; ++j)
        preB[(size_t)(row + j) * 512 + col] = f2u(acc[m][n][j]);
    }
}

// ---------------------------------------------------------------------------
extern "C" void kernel_launch(void* const* d_in, const int* in_sizes, int n_in,
                              void* d_out, int out_size, void* d_ws, size_t ws_size,
                              hipStream_t stream) {
  const float* q = (const float*)d_in[0];      // [8,2048,512]
  const float* s = (const float*)d_in[1];      // [8,2048,512]
  const int* mask = (const int*)d_in[2];       // [8,1,2048]
  const float* w = (const float*)d_in[3];      // [512,512]
  const float* out_w = (const float*)d_in[4];  // [512,512]
  const float* out_b = (const float*)d_in[5];  // [512]

  float* attn_w = (float*)d_out;                              // [8,2048,2048]
  float* attn_out = (float*)d_out + (size_t)8 * 2048 * 2048;  // [8,2048,512]

  char* ws = (char*)d_ws;
  const size_t MB = 1024 * 1024;
  unsigned short* qw  = (unsigned short*)(ws);            // [16384,512] bf16
  unsigned short* sN  = (unsigned short*)(ws + 17 * MB);  // [8,2048,512] bf16
  unsigned short* sTs = (unsigned short*)(ws + 34 * MB);  // [8,512,2048] swizzled
  unsigned short* pre = (unsigned short*)(ws + 51 * MB);  // [16384,512] bf16
  float2* statp       = (float2*)(ws + 51 * MB);          // [16384,32] (overlays pre)
  unsigned short* wT  = (unsigned short*)(ws + 68 * MB);  // [512,512] w^T
  unsigned short* owN = (unsigned short*)(ws + 68 * MB + 512 * 1024);
  float2* fstat       = (float2*)(ws + 69 * MB);          // [16384]

  dim3 tb(32, 8);
  cast_nt<1><<<dim3(16, 64, 8), tb, 0, stream>>>(s, sN, sTs, 2048, 512);
  cast_nt<0><<<dim3(16, 16, 1), tb, 0, stream>>>(w, nullptr, wT, 512, 512);
  cast_nt<0><<<dim3(16, 16, 1), tb, 0, stream>>>(out_w, owN, nullptr, 512, 512);

  // GEMM1: qw = q @ w (bf16 linear)
  gemm_bt<1, 0><<<dim3(4, 128, 1), 256, 0, stream>>>(q, wT, qw, nullptr, 512, 512);

  // scores + mask + partial stats; raw fp16 packed into attn_w rows
  gemm_sc<<<dim3(16, 16, 8), 256, 0, stream>>>(qw, sN, mask, attn_w, statp);

  // stats combine
  finalize_stats<<<64, 256, 0, stream>>>(statp, fstat);

  // in-place normalize + PV
  pv_norm<<<256, 512, 0, stream>>>(attn_w, sTs, fstat, pre);

  // GEMM4: attn_out = pre @ out_w^T + out_b
  gemm_bt<0, 2><<<dim3(4, 128, 1), 256, 0, stream>>>(pre, owN, attn_out, out_b, 512, 512);

  (void)in_sizes; (void)n_in; (void)out_size; (void)ws_size;
}